// Round 7
// baseline (291.819 us; speedup 1.0000x reference)
//
#include <hip/hip_runtime.h>
#include <hip/hip_bf16.h>
#include <math.h>

// Problem constants: N=100000 nodes, E=300000 edges, F=256.
#define FDIM 256

typedef short bfrag __attribute__((ext_vector_type(8)));   // 8 bf16 (4 VGPR)
typedef short s16x4 __attribute__((ext_vector_type(4)));
typedef float f32x4 __attribute__((ext_vector_type(4)));
typedef unsigned short u16x8 __attribute__((ext_vector_type(8)));

__device__ __forceinline__ short f2bf_rne(float f) {
    uint32_t u = __float_as_uint(f);
    uint32_t r = (u + 0x7FFFu + ((u >> 16) & 1u)) >> 16;
    return (short)r;
}
__device__ __forceinline__ float bf2f(unsigned short s) {
    return __uint_as_float(((uint32_t)s) << 16);
}

// ---------------------------------------------------------------------------
// CSR build: count -> scan (3 kernels) -> fill. Grouped by destination node.
// ---------------------------------------------------------------------------
__global__ void count_kernel(const int* __restrict__ dst, int* __restrict__ counts, int E) {
    int e = blockIdx.x * 256 + threadIdx.x;
    if (e < E) atomicAdd(&counts[dst[e]], 1);
}

__global__ void scan1_kernel(const int* __restrict__ counts, int* __restrict__ blksums, int N) {
    __shared__ int sd[256];
    int tid = threadIdx.x;
    int base = blockIdx.x * 1024 + tid * 4;
    int s = 0;
#pragma unroll
    for (int t = 0; t < 4; ++t) { int i = base + t; if (i < N) s += counts[i]; }
    sd[tid] = s; __syncthreads();
    for (int off = 128; off > 0; off >>= 1) {
        if (tid < off) sd[tid] += sd[tid + off];
        __syncthreads();
    }
    if (tid == 0) blksums[blockIdx.x] = sd[0];
}

__global__ void scan2_kernel(int* __restrict__ blksums, int NB) {
    __shared__ int sd[128];
    int tid = threadIdx.x;
    int v = (tid < NB) ? blksums[tid] : 0;
    sd[tid] = v; __syncthreads();
    for (int off = 1; off < 128; off <<= 1) {
        int t = (tid >= off) ? sd[tid - off] : 0;
        __syncthreads();
        sd[tid] += t;
        __syncthreads();
    }
    if (tid < NB) blksums[tid] = sd[tid] - v;   // exclusive
}

__global__ void scan3_kernel(const int* __restrict__ counts, const int* __restrict__ blksums,
                             int* __restrict__ offsets, int* __restrict__ cursor,
                             float* __restrict__ dinv, int N, int E) {
    __shared__ int sd[256];
    int tid = threadIdx.x;
    int base = blockIdx.x * 1024 + tid * 4;
    int c[4]; int s = 0;
#pragma unroll
    for (int t = 0; t < 4; ++t) { int i = base + t; c[t] = (i < N) ? counts[i] : 0; s += c[t]; }
    sd[tid] = s; __syncthreads();
    int v = s;
    for (int off = 1; off < 256; off <<= 1) {
        int t = (tid >= off) ? sd[tid - off] : 0;
        __syncthreads();
        sd[tid] += t;
        __syncthreads();
    }
    int run = sd[tid] - v + blksums[blockIdx.x];
#pragma unroll
    for (int t = 0; t < 4; ++t) {
        int i = base + t;
        if (i < N) {
            offsets[i] = run;
            cursor[i]  = run;
            dinv[i] = rsqrtf((float)(c[t] + 1));   // degree includes self loop
            run += c[t];
        }
    }
    if (blockIdx.x == 0 && tid == 0) offsets[N] = E;
}

__global__ void fill_kernel(const int* __restrict__ src, const int* __restrict__ dst,
                            int* __restrict__ cursor, int* __restrict__ csr_src, int E) {
    int e = blockIdx.x * 256 + threadIdx.x;
    if (e < E) {
        int s = src[e], d = dst[e];
        int pos = atomicAdd(&cursor[d], 1);
        csr_src[pos] = s;
    }
}

// ---------------------------------------------------------------------------
// W pre-split: W[k][n] fp32 -> hi/lo bf16, layout [s][n][g][8]:
//   idx = s*8192 + n*32 + g*8 + j   with k = s*32 + g*8 + j.
// A B-fragment (wn,ni,g,s) is then ONE coalesced 1KB wave-read from global:
// lane g*16+r15 loads dwordx4 at idx = s*8192 + (wn*64+ni*16+r15)*32 + g*8.
// ---------------------------------------------------------------------------
__global__ void wsplit_kernel(const float* __restrict__ W,
                              short* __restrict__ Wh, short* __restrict__ Wl) {
    const int k = blockIdx.x;       // 0..255
    const int n = threadIdx.x;      // 0..255
    const float w = W[k * 256 + n];
    const short hi = f2bf_rne(w);
    const short lo = f2bf_rne(w - bf2f((unsigned short)hi));
    const int s = k >> 5, g = (k & 31) >> 3, j = k & 7;
    const size_t idx = (size_t)s * 8192 + n * 32 + g * 8 + j;
    Wh[idx] = hi; Wl[idx] = lo;
}

// ---------------------------------------------------------------------------
// Split-bf16 MFMA GEMM:  h = (Xhi*Whi + Xhi*Wlo + Xlo*Whi) * dinv[row] -> bf16
// BM=64, BN=256, BK=32; 512 threads = 8 waves (2M x 4N), wave tile 32x64.
// W is NOT staged in LDS: B-fragments load straight global->VGPR (coalesced
// 1KB/wave from L2-resident pre-arranged W), prefetched one K-step ahead.
// Only X goes through LDS (16KB dbuf), layout [g][row][8] -> A-frag reads are
// 16-lane-contiguous (conflict-free). One barrier per K-step, no vmem drain.
// ---------------------------------------------------------------------------
__global__ __launch_bounds__(512, 4) void gemm_mfma(const float* __restrict__ X,
                                                    const short* __restrict__ Wth,
                                                    const short* __restrict__ Wtl,
                                                    const float* __restrict__ dinv,
                                                    unsigned short* __restrict__ Hb, int N) {
    __shared__ short Xh[2][2048], Xl[2][2048];   // [buf][g 0..3][row 0..63][8]

    const int tid  = threadIdx.x;
    const int lane = tid & 63;
    const int wid  = tid >> 6;          // 0..7
    const int wm   = wid >> 2;          // 0..1 -> rows wm*32
    const int wn   = wid & 3;           // 0..3 -> cols wn*64
    const int row0 = blockIdx.x * 64;
    const int g    = lane >> 4;
    const int r15  = lane & 15;

    // B fragment pointers: per-lane constant offset; s and ni are immediates
    const short* WhP = Wth + (wn * 64 + r15) * 32 + g * 8;
    const short* WlP = Wtl + (wn * 64 + r15) * 32 + g * 8;

    // X staging: thread owns row srow, float4 chunk skq (perfectly coalesced:
    // 8 threads cover one 128B row). LDS short-idx (g=skq>>1):
    const int srow = tid >> 3, skq = tid & 7;
    const int xsidx = (skq >> 1) * 512 + srow * 8 + (skq & 1) * 4;
    const int xrow = row0 + srow;
    const float* xptr = X + (size_t)xrow * FDIM + skq * 4;

    f32x4 acc[2][4];
#pragma unroll
    for (int i = 0; i < 2; ++i)
#pragma unroll
        for (int j = 0; j < 4; ++j) acc[i][j] = (f32x4){0.f, 0.f, 0.f, 0.f};

    bfrag bh[2][4], bl[2][4];

    // ---- prologue: stage X s=0, load B s=0, issue X s=1
    float4 xa = (xrow < N) ? *(const float4*)xptr : make_float4(0, 0, 0, 0);
    {
        const float v[4] = {xa.x, xa.y, xa.z, xa.w};
        s16x4 hi4, lo4;
#pragma unroll
        for (int j = 0; j < 4; ++j) {
            const short h = f2bf_rne(v[j]);
            hi4[j] = h; lo4[j] = f2bf_rne(v[j] - bf2f((unsigned short)h));
        }
        *(s16x4*)(&Xh[0][xsidx]) = hi4;
        *(s16x4*)(&Xl[0][xsidx]) = lo4;
    }
#pragma unroll
    for (int ni = 0; ni < 4; ++ni) {
        bh[0][ni] = *(const bfrag*)(WhP + ni * 512);
        bl[0][ni] = *(const bfrag*)(WlP + ni * 512);
    }
    xa = (xrow < N) ? *(const float4*)(xptr + 32) : make_float4(0, 0, 0, 0);
    __syncthreads();

#pragma unroll
    for (int s = 0; s < 8; ++s) {
        const int cur = s & 1, nxt = cur ^ 1;

        // ---- stage X for s+1 (ds_write into nxt; readers sync at barrier)
        if (s < 7) {
            const float v[4] = {xa.x, xa.y, xa.z, xa.w};
            s16x4 hi4, lo4;
#pragma unroll
            for (int j = 0; j < 4; ++j) {
                const short h = f2bf_rne(v[j]);
                hi4[j] = h; lo4[j] = f2bf_rne(v[j] - bf2f((unsigned short)h));
            }
            *(s16x4*)(&Xh[nxt][xsidx]) = hi4;
            *(s16x4*)(&Xl[nxt][xsidx]) = lo4;
        }
        if (s < 6)
            xa = (xrow < N) ? *(const float4*)(xptr + (s + 2) * 32) : make_float4(0, 0, 0, 0);

        // ---- prefetch B fragments for s+1 (latency spans this MFMA cluster)
        if (s < 7) {
#pragma unroll
            for (int ni = 0; ni < 4; ++ni) {
                bh[nxt][ni] = *(const bfrag*)(WhP + (s + 1) * 8192 + ni * 512);
                bl[nxt][ni] = *(const bfrag*)(WlP + (s + 1) * 8192 + ni * 512);
            }
        }

        // ---- A fragments from LDS (16-lane-contiguous, conflict-free)
        bfrag ah[2], al[2];
#pragma unroll
        for (int mi = 0; mi < 2; ++mi) {
            const int off = g * 512 + (wm * 32 + mi * 16 + r15) * 8;
            ah[mi] = *(const bfrag*)(&Xh[cur][off]);
            al[mi] = *(const bfrag*)(&Xl[cur][off]);
        }

        // ---- product-major MFMA (dep distance 8)
#pragma unroll
        for (int mi = 0; mi < 2; ++mi)
#pragma unroll
            for (int ni = 0; ni < 4; ++ni)
                acc[mi][ni] = __builtin_amdgcn_mfma_f32_16x16x32_bf16(ah[mi], bh[cur][ni], acc[mi][ni], 0, 0, 0);
#pragma unroll
        for (int mi = 0; mi < 2; ++mi)
#pragma unroll
            for (int ni = 0; ni < 4; ++ni)
                acc[mi][ni] = __builtin_amdgcn_mfma_f32_16x16x32_bf16(ah[mi], bl[cur][ni], acc[mi][ni], 0, 0, 0);
#pragma unroll
        for (int mi = 0; mi < 2; ++mi)
#pragma unroll
            for (int ni = 0; ni < 4; ++ni)
                acc[mi][ni] = __builtin_amdgcn_mfma_f32_16x16x32_bf16(al[mi], bh[cur][ni], acc[mi][ni], 0, 0, 0);

        if (s < 7) __syncthreads();
    }

    // ---- epilogue: D layout col=lane&15, row=(lane>>4)*4+reg; store bf16*dinv
#pragma unroll
    for (int mi = 0; mi < 2; ++mi) {
        const int rowb = row0 + wm * 32 + mi * 16 + g * 4;
#pragma unroll
        for (int r = 0; r < 4; ++r) {
            const int row = rowb + r;
            if (row < N) {
                const float dv = dinv[row];
                unsigned short* base = Hb + (size_t)row * FDIM + wn * 64 + r15;
#pragma unroll
                for (int ni = 0; ni < 4; ++ni)
                    base[ni * 16] = (unsigned short)f2bf_rne(acc[mi][ni][r] * dv);
            }
        }
    }
}

// ---------------------------------------------------------------------------
// Fused aggregation: one 16-lane group per node (16 nodes/block), 2-way ILP
// (two accumulator chains -> 4 outstanding 16B gathers per group).
// hb rows are pre-scaled by dinv[src]; result = dinv[dst]*sum + b_conv,
// then ReLU, dot W_lin, + b_lin, sigmoid -> out[node].
// ---------------------------------------------------------------------------
__global__ __launch_bounds__(256) void agg_kernel(const unsigned short* __restrict__ hb,
                                                  const int* __restrict__ offsets,
                                                  const int* __restrict__ csr_src,
                                                  const float* __restrict__ dinv,
                                                  const float* __restrict__ b_conv,
                                                  const float* __restrict__ W_lin,
                                                  const float* __restrict__ b_lin,
                                                  float* __restrict__ out, int N) {
    const int t    = threadIdx.x;
    const int l16  = t & 15;
    const int node = blockIdx.x * 16 + (t >> 4);
    if (node >= N) return;

    const int start = offsets[node];
    const int end   = offsets[node + 1];

    float accA[16], accB[16];
    {   // self loop row seeds chain A; chain B zero
        const unsigned short* r = hb + (size_t)node * FDIM + l16 * 16;
        const u16x8 u0 = *(const u16x8*)r, u1 = *(const u16x8*)(r + 8);
#pragma unroll
        for (int k = 0; k < 8; ++k) {
            accA[k] = bf2f(u0[k]); accA[8 + k] = bf2f(u1[k]);
            accB[k] = 0.f;         accB[8 + k] = 0.f;
        }
    }
    int j = start;
    for (; j + 1 < end; j += 2) {
        const unsigned short* ra = hb + (size_t)csr_src[j]     * FDIM + l16 * 16;
        const unsigned short* rb = hb + (size_t)csr_src[j + 1] * FDIM + l16 * 16;
        const u16x8 a0 = *(const u16x8*)ra, a1 = *(const u16x8*)(ra + 8);
        const u16x8 b0 = *(const u16x8*)rb, b1 = *(const u16x8*)(rb + 8);
#pragma unroll
        for (int k = 0; k < 8; ++k) {
            accA[k] += bf2f(a0[k]); accA[8 + k] += bf2f(a1[k]);
            accB[k] += bf2f(b0[k]); accB[8 + k] += bf2f(b1[k]);
        }
    }
    if (j < end) {
        const unsigned short* ra = hb + (size_t)csr_src[j] * FDIM + l16 * 16;
        const u16x8 a0 = *(const u16x8*)ra, a1 = *(const u16x8*)(ra + 8);
#pragma unroll
        for (int k = 0; k < 8; ++k) { accA[k] += bf2f(a0[k]); accA[8 + k] += bf2f(a1[k]); }
    }

    const float dv = dinv[node];
    float p = 0.f;
#pragma unroll
    for (int q = 0; q < 4; ++q) {
        const float4 bc = *(const float4*)(b_conv + l16 * 16 + q * 4);
        const float4 wl = *(const float4*)(W_lin  + l16 * 16 + q * 4);
        p = fmaf(fmaxf(fmaf(accA[q * 4 + 0] + accB[q * 4 + 0], dv, bc.x), 0.f), wl.x, p);
        p = fmaf(fmaxf(fmaf(accA[q * 4 + 1] + accB[q * 4 + 1], dv, bc.y), 0.f), wl.y, p);
        p = fmaf(fmaxf(fmaf(accA[q * 4 + 2] + accB[q * 4 + 2], dv, bc.z), 0.f), wl.z, p);
        p = fmaf(fmaxf(fmaf(accA[q * 4 + 3] + accB[q * 4 + 3], dv, bc.w), 0.f), wl.w, p);
    }
#pragma unroll
    for (int off = 1; off < 16; off <<= 1) p += __shfl_xor(p, off);
    if (l16 == 0) out[node] = 1.f / (1.f + expf(-(p + b_lin[0])));
}

// ---------------------------------------------------------------------------
extern "C" void kernel_launch(void* const* d_in, const int* in_sizes, int n_in,
                              void* d_out, int out_size, void* d_ws, size_t ws_size,
                              hipStream_t stream) {
    const float* x      = (const float*)d_in[0];
    const int*   eidx   = (const int*)d_in[1];
    const float* W_conv = (const float*)d_in[2];
    const float* b_conv = (const float*)d_in[3];
    const float* W_lin  = (const float*)d_in[4];
    const float* b_lin  = (const float*)d_in[5];
    float* out = (float*)d_out;

    const int N = in_sizes[0] / FDIM;      // 100000
    const int E = in_sizes[1] / 2;         // 300000
    const int* e_src = eidx;
    const int* e_dst = eidx + E;

    // workspace layout
    char* p = (char*)d_ws;
    unsigned short* hb = (unsigned short*)p; p += (size_t)N * FDIM * sizeof(unsigned short);
    int* counts   = (int*)p;        p += (size_t)N * sizeof(int);
    int* offsets  = (int*)p;        p += (size_t)(N + 1) * sizeof(int);
    int* cursor   = (int*)p;        p += (size_t)N * sizeof(int);
    float* dinv   = (float*)p;      p += (size_t)N * sizeof(float);
    int* csr_src  = (int*)p;        p += (size_t)E * sizeof(int);
    int* blksums  = (int*)p;        p += 128 * sizeof(int);
    short* Wth    = (short*)p;      p += (size_t)FDIM * FDIM * sizeof(short);
    short* Wtl    = (short*)p;      p += (size_t)FDIM * FDIM * sizeof(short);

    const int NB = (N + 1023) / 1024;

    hipMemsetAsync(counts, 0, (size_t)N * sizeof(int), stream);

    count_kernel<<<(E + 255) / 256, 256, 0, stream>>>(e_dst, counts, E);
    scan1_kernel<<<NB, 256, 0, stream>>>(counts, blksums, N);
    scan2_kernel<<<1, 128, 0, stream>>>(blksums, NB);
    scan3_kernel<<<NB, 256, 0, stream>>>(counts, blksums, offsets, cursor, dinv, N, E);
    fill_kernel<<<(E + 255) / 256, 256, 0, stream>>>(e_src, e_dst, cursor, csr_src, E);

    wsplit_kernel<<<FDIM, FDIM, 0, stream>>>(W_conv, Wth, Wtl);

    gemm_mfma<<<(N + 63) / 64, 512, 0, stream>>>(x, Wth, Wtl, dinv, hb, N);

    agg_kernel<<<(N + 15) / 16, 256, 0, stream>>>(hb, offsets, csr_src, dinv,
                                                  b_conv, W_lin, b_lin, out, N);
}

// Round 8
// 277.680 us; speedup vs baseline: 1.0509x; 1.0509x over previous
//
#include <hip/hip_runtime.h>
#include <hip/hip_bf16.h>
#include <math.h>

// Problem constants: N=100000 nodes, E=300000 edges, F=256.
#define FDIM 256

typedef short bfrag __attribute__((ext_vector_type(8)));   // 8 bf16 (4 VGPR)
typedef float f32x4 __attribute__((ext_vector_type(4)));
typedef unsigned short u16x8 __attribute__((ext_vector_type(8)));

__device__ __forceinline__ short f2bf_rne(float f) {
    uint32_t u = __float_as_uint(f);
    uint32_t r = (u + 0x7FFFu + ((u >> 16) & 1u)) >> 16;
    return (short)r;
}
__device__ __forceinline__ float bf2f(unsigned short s) {
    return __uint_as_float(((uint32_t)s) << 16);
}

#define GLOAD_LDS16(g, l) __builtin_amdgcn_global_load_lds(              \
    (const __attribute__((address_space(1))) void*)(g),                  \
    (__attribute__((address_space(3))) void*)(l), 16, 0, 0)

// ---------------------------------------------------------------------------
// CSR build: count -> scan (3 kernels) -> fill. Grouped by destination node.
// ---------------------------------------------------------------------------
__global__ void count_kernel(const int* __restrict__ dst, int* __restrict__ counts, int E) {
    int e = blockIdx.x * 256 + threadIdx.x;
    if (e < E) atomicAdd(&counts[dst[e]], 1);
}

__global__ void scan1_kernel(const int* __restrict__ counts, int* __restrict__ blksums, int N) {
    __shared__ int sd[256];
    int tid = threadIdx.x;
    int base = blockIdx.x * 1024 + tid * 4;
    int s = 0;
#pragma unroll
    for (int t = 0; t < 4; ++t) { int i = base + t; if (i < N) s += counts[i]; }
    sd[tid] = s; __syncthreads();
    for (int off = 128; off > 0; off >>= 1) {
        if (tid < off) sd[tid] += sd[tid + off];
        __syncthreads();
    }
    if (tid == 0) blksums[blockIdx.x] = sd[0];
}

__global__ void scan2_kernel(int* __restrict__ blksums, int NB) {
    __shared__ int sd[128];
    int tid = threadIdx.x;
    int v = (tid < NB) ? blksums[tid] : 0;
    sd[tid] = v; __syncthreads();
    for (int off = 1; off < 128; off <<= 1) {
        int t = (tid >= off) ? sd[tid - off] : 0;
        __syncthreads();
        sd[tid] += t;
        __syncthreads();
    }
    if (tid < NB) blksums[tid] = sd[tid] - v;   // exclusive
}

__global__ void scan3_kernel(const int* __restrict__ counts, const int* __restrict__ blksums,
                             int* __restrict__ offsets, int* __restrict__ cursor,
                             float* __restrict__ dinv, int N, int E) {
    __shared__ int sd[256];
    int tid = threadIdx.x;
    int base = blockIdx.x * 1024 + tid * 4;
    int c[4]; int s = 0;
#pragma unroll
    for (int t = 0; t < 4; ++t) { int i = base + t; c[t] = (i < N) ? counts[i] : 0; s += c[t]; }
    sd[tid] = s; __syncthreads();
    int v = s;
    for (int off = 1; off < 256; off <<= 1) {
        int t = (tid >= off) ? sd[tid - off] : 0;
        __syncthreads();
        sd[tid] += t;
        __syncthreads();
    }
    int run = sd[tid] - v + blksums[blockIdx.x];
#pragma unroll
    for (int t = 0; t < 4; ++t) {
        int i = base + t;
        if (i < N) {
            offsets[i] = run;
            cursor[i]  = run;
            dinv[i] = rsqrtf((float)(c[t] + 1));   // degree includes self loop
            run += c[t];
        }
    }
    if (blockIdx.x == 0 && tid == 0) offsets[N] = E;
}

__global__ void fill_kernel(const int* __restrict__ src, const int* __restrict__ dst,
                            int* __restrict__ cursor, int* __restrict__ csr_src, int E) {
    int e = blockIdx.x * 256 + threadIdx.x;
    if (e < E) {
        int s = src[e], d = dst[e];
        int pos = atomicAdd(&cursor[d], 1);
        csr_src[pos] = s;
    }
}

// ---------------------------------------------------------------------------
// W pre-split: W[k][n] fp32 -> hi/lo bf16, SWIZZLED layout for bank-free LDS:
//   base_short = n*32 + g*8   (k = s*32 + g*8 + j)
//   idx = s*8192 + (base_short ^ ((n&7)<<3)) + j
// The XOR folds n's low bits into the bank index; gemm stages each 16KB chunk
// linearly via global_load_lds (source pre-swizzled, LDS dest linear = m173
// pattern), and B-frag ds_read_b128 spread over 8 banks (2-way = free).
// ---------------------------------------------------------------------------
__global__ void wsplit_kernel(const float* __restrict__ W,
                              short* __restrict__ Wh, short* __restrict__ Wl) {
    const int k = blockIdx.x;       // 0..255
    const int n = threadIdx.x;      // 0..255
    const float w = W[k * 256 + n];
    const short hi = f2bf_rne(w);
    const short lo = f2bf_rne(w - bf2f((unsigned short)hi));
    const int s = k >> 5, g = (k & 31) >> 3, j = k & 7;
    const size_t idx = (size_t)s * 8192 + ((n * 32 + g * 8) ^ ((n & 7) << 3)) + j;
    Wh[idx] = hi; Wl[idx] = lo;
}

// ---------------------------------------------------------------------------
// Split-bf16 MFMA GEMM:  h = (Xhi*Whi + Xhi*Wlo + Xlo*Whi) * dinv[row] -> bf16
// BM=128, BN=256, BK=32; 512 threads = 8 waves (2M x 4N), wave tile 64x64.
// Per wave-K-step: 48 MFMA vs 16 ds_read_b128 (3:1) -> MFMA-bound steady state
// (per block-K-step: MFMA ~1860cy > LDS ~1100cy).
// LDS 96KB (X 32K + W 64K, dbuf) -> 1 block/CU; pipeline hides staging.
// W LDS is XOR-swizzled (see wsplit); X layout [g][row][8] -> A-frag reads
// 2-way only. One barrier per K-step; staging issued before MFMA cluster.
// ---------------------------------------------------------------------------
__global__ __launch_bounds__(512, 2) void gemm_mfma(const float* __restrict__ X,
                                                    const short* __restrict__ Wth,
                                                    const short* __restrict__ Wtl,
                                                    const float* __restrict__ dinv,
                                                    unsigned short* __restrict__ Hb, int N) {
    __shared__ short Xh[2][4096], Xl[2][4096];   // [buf][g 0..3][row 0..127][8]
    __shared__ short Wh[2][8192], Wl[2][8192];   // [buf][swizzled n,g][8]

    const int tid  = threadIdx.x;
    const int lane = tid & 63;
    const int wid  = tid >> 6;          // 0..7
    const int wm   = wid >> 2;          // 0..1 -> rows wm*64
    const int wn   = wid & 3;           // 0..3 -> cols wn*64
    const int row0 = blockIdx.x * 128;
    const int g    = lane >> 4;
    const int r15  = lane & 15;
    const int bswz = (r15 & 7) << 3;    // B-frag short-index XOR

    // X staging: thread owns row srow, 8-float chunk sc (coalesced 128B/4 thr)
    const int srow = tid >> 2, sc = tid & 3;
    const int xsidx = sc * 1024 + srow * 8;      // [g=sc][srow][8] shorts
    const int xrow = row0 + srow;
    const float* xptr = X + (size_t)xrow * FDIM + 8 * sc;

    f32x4 acc[4][4];
#pragma unroll
    for (int i = 0; i < 4; ++i)
#pragma unroll
        for (int j = 0; j < 4; ++j) acc[i][j] = (f32x4){0.f, 0.f, 0.f, 0.f};

    float4 xa0, xa1;
    // ---- prologue: stage s=0 (X regs->LDS, W gload_lds), issue X s=1
    if (xrow < N) { xa0 = *(const float4*)xptr; xa1 = *(const float4*)(xptr + 4); }
    else          { xa0 = make_float4(0,0,0,0); xa1 = make_float4(0,0,0,0); }
    {
        const float v[8] = {xa0.x,xa0.y,xa0.z,xa0.w,xa1.x,xa1.y,xa1.z,xa1.w};
        bfrag hi8, lo8;
#pragma unroll
        for (int j = 0; j < 8; ++j) {
            const short h = f2bf_rne(v[j]);
            hi8[j] = h; lo8[j] = f2bf_rne(v[j] - bf2f((unsigned short)h));
        }
        *(bfrag*)(&Xh[0][xsidx]) = hi8;
        *(bfrag*)(&Xl[0][xsidx]) = lo8;
    }
#pragma unroll
    for (int p = 0; p < 2; ++p) {
        GLOAD_LDS16(Wth + p * 4096 + tid * 8, &Wh[0][p * 4096 + tid * 8]);
        GLOAD_LDS16(Wtl + p * 4096 + tid * 8, &Wl[0][p * 4096 + tid * 8]);
    }
    if (xrow < N) { xa0 = *(const float4*)(xptr + 32); xa1 = *(const float4*)(xptr + 36); }
    else          { xa0 = make_float4(0,0,0,0); xa1 = make_float4(0,0,0,0); }
    __syncthreads();

#pragma unroll
    for (int s = 0; s < 8; ++s) {
        const int cur = s & 1, nxt = cur ^ 1;

        // ---- stage s+1 (issued first; latency spans this iter's MFMAs)
        if (s < 7) {
            const float v[8] = {xa0.x,xa0.y,xa0.z,xa0.w,xa1.x,xa1.y,xa1.z,xa1.w};
            bfrag hi8, lo8;
#pragma unroll
            for (int j = 0; j < 8; ++j) {
                const short h = f2bf_rne(v[j]);
                hi8[j] = h; lo8[j] = f2bf_rne(v[j] - bf2f((unsigned short)h));
            }
            *(bfrag*)(&Xh[nxt][xsidx]) = hi8;
            *(bfrag*)(&Xl[nxt][xsidx]) = lo8;
            const short* gh = Wth + (s + 1) * 8192;
            const short* gl = Wtl + (s + 1) * 8192;
#pragma unroll
            for (int p = 0; p < 2; ++p) {
                GLOAD_LDS16(gh + p * 4096 + tid * 8, &Wh[nxt][p * 4096 + tid * 8]);
                GLOAD_LDS16(gl + p * 4096 + tid * 8, &Wl[nxt][p * 4096 + tid * 8]);
            }
        }
        if (s < 6) {
            if (xrow < N) {
                const float* src = xptr + (s + 2) * 32;
                xa0 = *(const float4*)src; xa1 = *(const float4*)(src + 4);
            } else { xa0 = make_float4(0,0,0,0); xa1 = make_float4(0,0,0,0); }
        }

        // ---- fragments (A: 2-way bank-free; B: swizzled, 2-way)
        bfrag ah[4], al[4], bh[4], bl[4];
#pragma unroll
        for (int mi = 0; mi < 4; ++mi) {
            const int off = g * 1024 + (wm * 64 + mi * 16 + r15) * 8;
            ah[mi] = *(const bfrag*)(&Xh[cur][off]);
            al[mi] = *(const bfrag*)(&Xl[cur][off]);
        }
#pragma unroll
        for (int ni = 0; ni < 4; ++ni) {
            const int off = (((wn * 64 + ni * 16 + r15) * 32 + g * 8) ^ bswz);
            bh[ni] = *(const bfrag*)(&Wh[cur][off]);
            bl[ni] = *(const bfrag*)(&Wl[cur][off]);
        }

        // ---- product-major MFMA (16 independent MFMAs between acc reuses)
#pragma unroll
        for (int mi = 0; mi < 4; ++mi)
#pragma unroll
            for (int ni = 0; ni < 4; ++ni)
                acc[mi][ni] = __builtin_amdgcn_mfma_f32_16x16x32_bf16(ah[mi], bh[ni], acc[mi][ni], 0, 0, 0);
#pragma unroll
        for (int mi = 0; mi < 4; ++mi)
#pragma unroll
            for (int ni = 0; ni < 4; ++ni)
                acc[mi][ni] = __builtin_amdgcn_mfma_f32_16x16x32_bf16(ah[mi], bl[ni], acc[mi][ni], 0, 0, 0);
#pragma unroll
        for (int mi = 0; mi < 4; ++mi)
#pragma unroll
            for (int ni = 0; ni < 4; ++ni)
                acc[mi][ni] = __builtin_amdgcn_mfma_f32_16x16x32_bf16(al[mi], bh[ni], acc[mi][ni], 0, 0, 0);

        if (s < 7) __syncthreads();
    }

    // ---- epilogue: D layout col=lane&15, row=(lane>>4)*4+reg; store bf16*dinv
#pragma unroll
    for (int mi = 0; mi < 4; ++mi) {
        const int rowb = row0 + wm * 64 + mi * 16 + g * 4;
#pragma unroll
        for (int r = 0; r < 4; ++r) {
            const int row = rowb + r;
            if (row < N) {
                const float dv = dinv[row];
                unsigned short* base = Hb + (size_t)row * FDIM + wn * 64 + r15;
#pragma unroll
                for (int ni = 0; ni < 4; ++ni)
                    base[ni * 16] = (unsigned short)f2bf_rne(acc[mi][ni][r] * dv);
            }
        }
    }
}

// ---------------------------------------------------------------------------
// Fused aggregation: one 16-lane group per node. Indices preloaded in
// PARALLEL (lane l grabs csr_src[start+l]) and broadcast via __shfl, so row
// gathers are issued 4-at-a-time (8x16B in flight) with no index->gather
// dependency chain. hb rows pre-scaled by dinv[src]; result = dinv[dst]*sum
// + b_conv, ReLU, dot W_lin, + b_lin, sigmoid -> out[node].
// ---------------------------------------------------------------------------
__global__ __launch_bounds__(256) void agg_kernel(const unsigned short* __restrict__ hb,
                                                  const int* __restrict__ offsets,
                                                  const int* __restrict__ csr_src,
                                                  const float* __restrict__ dinv,
                                                  const float* __restrict__ b_conv,
                                                  const float* __restrict__ W_lin,
                                                  const float* __restrict__ b_lin,
                                                  float* __restrict__ out, int N) {
    const int t    = threadIdx.x;
    const int l16  = t & 15;
    const int node = blockIdx.x * 16 + (t >> 4);
    if (node >= N) return;

    const int start = offsets[node];
    const int end   = offsets[node + 1];
    const int deg   = end - start;

    // parallel preload of up to 16 neighbor indices
    int idx16 = (l16 < deg) ? csr_src[start + l16] : 0;

    float acc[16];
    {   // self loop row
        const unsigned short* r = hb + (size_t)node * FDIM + l16 * 16;
        const u16x8 u0 = *(const u16x8*)r, u1 = *(const u16x8*)(r + 8);
#pragma unroll
        for (int k = 0; k < 8; ++k) { acc[k] = bf2f(u0[k]); acc[8 + k] = bf2f(u1[k]); }
    }

    const int dcap = deg < 16 ? deg : 16;
    int k = 0;
    for (; k + 4 <= dcap; k += 4) {   // 4 rows per iteration, 8 loads in flight
        const int s0 = __shfl(idx16, k,     16);
        const int s1 = __shfl(idx16, k + 1, 16);
        const int s2 = __shfl(idx16, k + 2, 16);
        const int s3 = __shfl(idx16, k + 3, 16);
        const unsigned short* r0 = hb + (size_t)s0 * FDIM + l16 * 16;
        const unsigned short* r1 = hb + (size_t)s1 * FDIM + l16 * 16;
        const unsigned short* r2 = hb + (size_t)s2 * FDIM + l16 * 16;
        const unsigned short* r3 = hb + (size_t)s3 * FDIM + l16 * 16;
        const u16x8 a0 = *(const u16x8*)r0, a1 = *(const u16x8*)(r0 + 8);
        const u16x8 b0 = *(const u16x8*)r1, b1 = *(const u16x8*)(r1 + 8);
        const u16x8 c0 = *(const u16x8*)r2, c1 = *(const u16x8*)(r2 + 8);
        const u16x8 d0 = *(const u16x8*)r3, d1 = *(const u16x8*)(r3 + 8);
#pragma unroll
        for (int q = 0; q < 8; ++q) {
            acc[q]     += (bf2f(a0[q]) + bf2f(b0[q])) + (bf2f(c0[q]) + bf2f(d0[q]));
            acc[8 + q] += (bf2f(a1[q]) + bf2f(b1[q])) + (bf2f(c1[q]) + bf2f(d1[q]));
        }
    }
    for (; k < dcap; ++k) {
        const int s0 = __shfl(idx16, k, 16);
        const unsigned short* r = hb + (size_t)s0 * FDIM + l16 * 16;
        const u16x8 u0 = *(const u16x8*)r, u1 = *(const u16x8*)(r + 8);
#pragma unroll
        for (int q = 0; q < 8; ++q) { acc[q] += bf2f(u0[q]); acc[8 + q] += bf2f(u1[q]); }
    }
    for (int j = start + 16; j < end; ++j) {   // rare high-degree tail
        const unsigned short* r = hb + (size_t)csr_src[j] * FDIM + l16 * 16;
        const u16x8 u0 = *(const u16x8*)r, u1 = *(const u16x8*)(r + 8);
#pragma unroll
        for (int q = 0; q < 8; ++q) { acc[q] += bf2f(u0[q]); acc[8 + q] += bf2f(u1[q]); }
    }

    const float dv = dinv[node];
    float p = 0.f;
#pragma unroll
    for (int q = 0; q < 4; ++q) {
        const float4 bc = *(const float4*)(b_conv + l16 * 16 + q * 4);
        const float4 wl = *(const float4*)(W_lin  + l16 * 16 + q * 4);
        p = fmaf(fmaxf(fmaf(acc[q * 4 + 0], dv, bc.x), 0.f), wl.x, p);
        p = fmaf(fmaxf(fmaf(acc[q * 4 + 1], dv, bc.y), 0.f), wl.y, p);
        p = fmaf(fmaxf(fmaf(acc[q * 4 + 2], dv, bc.z), 0.f), wl.z, p);
        p = fmaf(fmaxf(fmaf(acc[q * 4 + 3], dv, bc.w), 0.f), wl.w, p);
    }
#pragma unroll
    for (int off = 1; off < 16; off <<= 1) p += __shfl_xor(p, off);
    if (l16 == 0) out[node] = 1.f / (1.f + expf(-(p + b_lin[0])));
}

// ---------------------------------------------------------------------------
extern "C" void kernel_launch(void* const* d_in, const int* in_sizes, int n_in,
                              void* d_out, int out_size, void* d_ws, size_t ws_size,
                              hipStream_t stream) {
    const float* x      = (const float*)d_in[0];
    const int*   eidx   = (const int*)d_in[1];
    const float* W_conv = (const float*)d_in[2];
    const float* b_conv = (const float*)d_in[3];
    const float* W_lin  = (const float*)d_in[4];
    const float* b_lin  = (const float*)d_in[5];
    float* out = (float*)d_out;

    const int N = in_sizes[0] / FDIM;      // 100000
    const int E = in_sizes[1] / 2;         // 300000
    const int* e_src = eidx;
    const int* e_dst = eidx + E;

    // workspace layout
    char* p = (char*)d_ws;
    unsigned short* hb = (unsigned short*)p; p += (size_t)N * FDIM * sizeof(unsigned short);
    int* counts   = (int*)p;        p += (size_t)N * sizeof(int);
    int* offsets  = (int*)p;        p += (size_t)(N + 1) * sizeof(int);
    int* cursor   = (int*)p;        p += (size_t)N * sizeof(int);
    float* dinv   = (float*)p;      p += (size_t)N * sizeof(float);
    int* csr_src  = (int*)p;        p += (size_t)E * sizeof(int);
    int* blksums  = (int*)p;        p += 128 * sizeof(int);
    short* Wth    = (short*)p;      p += (size_t)FDIM * FDIM * sizeof(short);
    short* Wtl    = (short*)p;      p += (size_t)FDIM * FDIM * sizeof(short);

    const int NB = (N + 1023) / 1024;

    hipMemsetAsync(counts, 0, (size_t)N * sizeof(int), stream);

    count_kernel<<<(E + 255) / 256, 256, 0, stream>>>(e_dst, counts, E);
    scan1_kernel<<<NB, 256, 0, stream>>>(counts, blksums, N);
    scan2_kernel<<<1, 128, 0, stream>>>(blksums, NB);
    scan3_kernel<<<NB, 256, 0, stream>>>(counts, blksums, offsets, cursor, dinv, N, E);
    fill_kernel<<<(E + 255) / 256, 256, 0, stream>>>(e_src, e_dst, cursor, csr_src, E);

    wsplit_kernel<<<FDIM, FDIM, 0, stream>>>(W_conv, Wth, Wtl);

    gemm_mfma<<<(N + 127) / 128, 512, 0, stream>>>(x, Wth, Wtl, dinv, hb, N);

    agg_kernel<<<(N + 15) / 16, 256, 0, stream>>>(hb, offsets, csr_src, dinv,
                                                  b_conv, W_lin, b_lin, out, N);
}